// Round 14
// baseline (1998.502 us; speedup 1.0000x reference)
//
#include <hip/hip_runtime.h>
#include <hip/hip_bf16.h>

#define B_ 2
#define S_ 1024
#define T_ (B_*S_)
#define D_ 2048
#define L_ 4
#define HQ_ 32
#define HKV_ 8
#define HD_ 64
#define I_ 5632
#define EPS_ 1e-5f
#define SCALE_ 0.125f

typedef __attribute__((ext_vector_type(4))) float  float4v;
typedef __attribute__((ext_vector_type(8))) short  short8v;
typedef __attribute__((ext_vector_type(4))) short  short4v;

#define GLOAD16(g, l) \
  __builtin_amdgcn_global_load_lds((const __attribute__((address_space(1))) void*)(g), \
                                   (__attribute__((address_space(3))) void*)(l), 16, 0, 0)

__device__ __forceinline__ short f2bf(float f) {
  union { float f; unsigned u; } c; c.f = f;
  unsigned u = c.u + 0x7fffu + ((c.u >> 16) & 1u);
  return (short)(u >> 16);
}

// bijective XCD-aware block swizzle (m204), column-major decode
__device__ __forceinline__ void xcd_swizzle(int gx, int gy, int& bx, int& by) {
  int nwg = gx * gy;
  int orig = by * gx + bx;
  int q = nwg >> 3, r = nwg & 7;
  int xcd = orig & 7, loc = orig >> 3;
  int swz = (xcd < r ? xcd * (q + 1) : r * (q + 1) + (xcd - r) * q) + loc;
  bx = swz / gy;
  by = swz - bx * gy;
}

// ------- ONE layer's weight transposes, no-LDS direct form -------
// Thread: 8 coalesced float4 row-reads (4 n-values x 8 k-rows held in regs),
// in-register transpose, 4x short8 stores along K.  Block = 256n x 32k.
__global__ __launch_bounds__(256)
void transpose_layer(const float* __restrict__ wq, const float* __restrict__ wo,
                     const float* __restrict__ wg, const float* __restrict__ wd,
                     short* __restrict__ tq, short* __restrict__ to_,
                     short* __restrict__ tg, short* __restrict__ td) {
  int id = blockIdx.x;
  const float* in; short* out; int K, N, bxt, byt;
  if (id < 768)       { in = wq; out = tq;
                        K = 2048; N = 3072;  bxt = id % 12; byt = id / 12; }
  else if (id < 1280) { id -= 768;  in = wo; out = to_;
                        K = 2048; N = 2048;  bxt = id % 8;  byt = id / 8; }
  else if (id < 4096) { id -= 1280; in = wg; out = tg;
                        K = 2048; N = 11264; bxt = id % 44; byt = id / 44; }
  else                { id -= 4096; in = wd; out = td;
                        K = 5632; N = 2048;  bxt = id % 8;  byt = id / 8; }
  const int tid  = threadIdx.x;
  const int lane = tid & 63;
  const int wv   = tid >> 6;
  const int n0 = bxt * 256 + lane * 4;
  const int k0 = byt * 32 + wv * 8;
  float4v v[8];
  #pragma unroll
  for (int e = 0; e < 8; e++)
    v[e] = *(const float4v*)(in + (size_t)(k0 + e) * N + n0);
  #pragma unroll
  for (int i = 0; i < 4; i++) {
    short8v y;
    #pragma unroll
    for (int e = 0; e < 8; e++) y[e] = f2bf(v[e][i]);
    *(short8v*)(out + (size_t)(n0 + i) * K + k0) = y;
  }
}

// ---------------- embedding gather ----------------
__global__ __launch_bounds__(256)
void embed_gather(const int* __restrict__ ids, const float* __restrict__ embed,
                  float* __restrict__ h) {
  size_t i = (size_t)blockIdx.x * 256 + threadIdx.x;
  int t  = (int)(i >> 9);
  int d4 = (int)(i & 511);
  ((float4v*)h)[i] = ((const float4v*)(embed + (size_t)ids[t] * D_))[d4];
}

// ------- RMSNorm: first -> res = x, else pure read of res; out f32/bf16 -------
__global__ __launch_bounds__(256)
void rmsnorm_kernel(const float* __restrict__ x, float* __restrict__ res,
                    const float* __restrict__ w, void* __restrict__ outp,
                    int first, int bf16out) {
  const int row = blockIdx.x;
  const int tid = threadIdx.x;
  const size_t base = (size_t)row * D_;
  float4v v0, v1;
  if (first) {
    v0 = ((const float4v*)(x + base))[tid * 2];
    v1 = ((const float4v*)(x + base))[tid * 2 + 1];
    ((float4v*)(res + base))[tid * 2]     = v0;
    ((float4v*)(res + base))[tid * 2 + 1] = v1;
  } else {
    v0 = ((const float4v*)(res + base))[tid * 2];
    v1 = ((const float4v*)(res + base))[tid * 2 + 1];
  }
  float ss = v0[0]*v0[0] + v0[1]*v0[1] + v0[2]*v0[2] + v0[3]*v0[3]
           + v1[0]*v1[0] + v1[1]*v1[1] + v1[2]*v1[2] + v1[3]*v1[3];
  #pragma unroll
  for (int off = 32; off > 0; off >>= 1) ss += __shfl_xor(ss, off, 64);
  __shared__ float red[4];
  if ((tid & 63) == 0) red[tid >> 6] = ss;
  __syncthreads();
  float tot = red[0] + red[1] + red[2] + red[3];
  float rs = rsqrtf(tot * (1.0f / D_) + EPS_);
  float4v w0 = ((const float4v*)w)[tid * 2];
  float4v w1 = ((const float4v*)w)[tid * 2 + 1];
  float4v o0 = v0 * rs * w0;
  float4v o1 = v1 * rs * w1;
  if (bf16out) {
    short8v y;
    #pragma unroll
    for (int k = 0; k < 4; k++) { y[k] = f2bf(o0[k]); y[k + 4] = f2bf(o1[k]); }
    ((short8v*)((char*)outp + base * 2))[tid] = y;
  } else {
    float* op = (float*)outp + base;
    ((float4v*)op)[tid * 2]     = o0;
    ((float4v*)op)[tid * 2 + 1] = o1;
  }
}

// ======== 128x128 8-wave GEMM, counted vmcnt(4) + T2 swizzle + setprio ========
__global__ __launch_bounds__(512, 4)
void gemm_big128(const short* __restrict__ A, const short* __restrict__ Bt,
                 float* __restrict__ C, int M, int N, int K, int addto) {
  __shared__ short sA[2][128 * 64];
  __shared__ short sB[2][128 * 64];
  int bx = blockIdx.x, by = blockIdx.y;
  xcd_swizzle(gridDim.x, gridDim.y, bx, by);
  const int tid  = threadIdx.x;
  const int lane = tid & 63;
  const int wv   = tid >> 6;
  const int wr   = wv >> 2;
  const int wc   = wv & 3;
  const int row0 = by * 128;
  const int col0 = bx * 128;
  const int fr = lane & 15;
  const int g  = lane >> 4;
  const int NT = K >> 6;

  float4v acc[4][2] = {};

  int rS[2], cS[2];
  #pragma unroll
  for (int k = 0; k < 2; k++) {
    int s = tid + k * 512;
    rS[k] = s >> 3;
    cS[k] = (((s & 7) ^ (rS[k] & 7)) << 3);
  }

#define STAGE128(t, buf) do { \
    int k0_ = (t) << 6; \
    _Pragma("unroll") \
    for (int k_ = 0; k_ < 2; k_++) \
      GLOAD16(A  + (size_t)(row0 + rS[k_]) * K + k0_ + cS[k_], \
              &sA[buf][(tid + k_ * 512) * 8]); \
    _Pragma("unroll") \
    for (int k_ = 0; k_ < 2; k_++) \
      GLOAD16(Bt + (size_t)(col0 + rS[k_]) * K + k0_ + cS[k_], \
              &sB[buf][(tid + k_ * 512) * 8]); \
  } while (0)

  STAGE128(0, 0);

  for (int t = 0; t < NT; t++) {
    const int cur = t & 1;
    if (t + 1 < NT) {
      STAGE128(t + 1, cur ^ 1);
      asm volatile("s_waitcnt vmcnt(4)" ::: "memory");
    } else {
      asm volatile("s_waitcnt vmcnt(0)" ::: "memory");
    }
    __builtin_amdgcn_s_barrier();
    __builtin_amdgcn_sched_barrier(0);

    const short* pA = &sA[cur][(wr * 64) * 64];
    const short* pB = &sB[cur][(wc * 32) * 64];
    #pragma unroll
    for (int ks = 0; ks < 2; ks++) {
      const int fswk = ((((ks << 2) | g) ^ (fr & 7)) << 3);
      short8v bfr[2], afr[4];
      #pragma unroll
      for (int ni = 0; ni < 2; ni++)
        bfr[ni] = *(const short8v*)(pB + (ni * 16 + fr) * 64 + fswk);
      #pragma unroll
      for (int m4 = 0; m4 < 4; m4++)
        afr[m4] = *(const short8v*)(pA + (m4 * 16 + fr) * 64 + fswk);
      __builtin_amdgcn_s_setprio(1);
      #pragma unroll
      for (int m4 = 0; m4 < 4; m4++)
        #pragma unroll
        for (int ni = 0; ni < 2; ni++)
          acc[m4][ni] = __builtin_amdgcn_mfma_f32_16x16x32_bf16(
              afr[m4], bfr[ni], acc[m4][ni], 0, 0, 0);
      __builtin_amdgcn_s_setprio(0);
    }
    asm volatile("" ::: "memory");
    __builtin_amdgcn_s_barrier();
  }

  #pragma unroll
  for (int m4 = 0; m4 < 4; m4++)
    #pragma unroll
    for (int ni = 0; ni < 2; ni++) {
      size_t base = (size_t)(row0 + wr * 64 + m4 * 16 + g * 4) * N
                    + col0 + wc * 32 + ni * 16 + fr;
      if (addto) {
        #pragma unroll
        for (int r = 0; r < 4; r++)
          C[base + (size_t)r * N] += acc[m4][ni][r];
      } else {
        #pragma unroll
        for (int r = 0; r < 4; r++)
          C[base + (size_t)r * N] = acc[m4][ni][r];
      }
    }
#undef STAGE128
}

// ======== gate_up GEMM + fused SwiGLU on the same schedule, vmcnt(6) ========
__global__ __launch_bounds__(512, 2)
void gemm_glu_big(const short* __restrict__ A, const short* __restrict__ Bt,
                  short* __restrict__ mlp, int K) {
  __shared__ short sA[2][128 * 64];
  __shared__ short sG[2][128 * 64];
  __shared__ short sU[2][128 * 64];
  int bx = blockIdx.x, by = blockIdx.y;
  xcd_swizzle(gridDim.x, gridDim.y, bx, by);
  const int tid  = threadIdx.x;
  const int lane = tid & 63;
  const int wv   = tid >> 6;
  const int wr   = wv >> 2;
  const int wc   = wv & 3;
  const int row0 = by * 128;
  const int col0 = bx * 128;
  const int fr = lane & 15;
  const int g  = lane >> 4;
  const int NT = K >> 6;

  float4v accg[4][2] = {};
  float4v accu[4][2] = {};

  int rS[2], cS[2];
  #pragma unroll
  for (int k = 0; k < 2; k++) {
    int s = tid + k * 512;
    rS[k] = s >> 3;
    cS[k] = (((s & 7) ^ (rS[k] & 7)) << 3);
  }

#define STAGEGLU(t, buf) do { \
    int k0_ = (t) << 6; \
    _Pragma("unroll") \
    for (int k_ = 0; k_ < 2; k_++) \
      GLOAD16(A  + (size_t)(row0 + rS[k_]) * K + k0_ + cS[k_], \
              &sA[buf][(tid + k_ * 512) * 8]); \
    _Pragma("unroll") \
    for (int k_ = 0; k_ < 2; k_++) \
      GLOAD16(Bt + (size_t)(col0 + rS[k_]) * K + k0_ + cS[k_], \
              &sG[buf][(tid + k_ * 512) * 8]); \
    _Pragma("unroll") \
    for (int k_ = 0; k_ < 2; k_++) \
      GLOAD16(Bt + (size_t)(col0 + I_ + rS[k_]) * K + k0_ + cS[k_], \
              &sU[buf][(tid + k_ * 512) * 8]); \
  } while (0)

  STAGEGLU(0, 0);

  for (int t = 0; t < NT; t++) {
    const int cur = t & 1;
    if (t + 1 < NT) {
      STAGEGLU(t + 1, cur ^ 1);
      asm volatile("s_waitcnt vmcnt(6)" ::: "memory");
    } else {
      asm volatile("s_waitcnt vmcnt(0)" ::: "memory");
    }
    __builtin_amdgcn_s_barrier();
    __builtin_amdgcn_sched_barrier(0);

    const short* pA = &sA[cur][(wr * 64) * 64];
    const short* pG = &sG[cur][(wc * 32) * 64];
    const short* pU = &sU[cur][(wc * 32) * 64];
    #pragma unroll
    for (int ks = 0; ks < 2; ks++) {
      const int fswk = ((((ks << 2) | g) ^ (fr & 7)) << 3);
      short8v bg[2], bu[2], afr[4];
      #pragma unroll
      for (int ni = 0; ni < 2; ni++) {
        bg[ni] = *(const short8v*)(pG + (ni * 16 + fr) * 64 + fswk);
        bu[ni] = *(const short8v*)(pU + (ni * 16 + fr) * 64 + fswk);
      }
      #pragma unroll
      for (int m4 = 0; m4 < 4; m4++)
        afr[m4] = *(const short8v*)(pA + (m4 * 16 + fr) * 64 + fswk);
      __builtin_amdgcn_s_setprio(1);
      #pragma unroll
      for (int m4 = 0; m4 < 4; m4++)
        #pragma unroll
        for (int ni = 0; ni < 2; ni++) {
          accg[m4][ni] = __builtin_amdgcn_mfma_f32_16x16x32_bf16(
              afr[m4], bg[ni], accg[m4][ni], 0, 0, 0);
          accu[m4][ni] = __builtin_amdgcn_mfma_f32_16x16x32_bf16(
              afr[m4], bu[ni], accu[m4][ni], 0, 0, 0);
        }
      __builtin_amdgcn_s_setprio(0);
    }
    asm volatile("" ::: "memory");
    __builtin_amdgcn_s_barrier();
  }

  #pragma unroll
  for (int m4 = 0; m4 < 4; m4++)
    #pragma unroll
    for (int ni = 0; ni < 2; ni++) {
      size_t base = (size_t)(row0 + wr * 64 + m4 * 16 + g * 4) * I_
                    + col0 + wc * 32 + ni * 16 + fr;
      #pragma unroll
      for (int r = 0; r < 4; r++) {
        float gv = accg[m4][ni][r], uv = accu[m4][ni][r];
        mlp[base + (size_t)r * I_] = f2bf(gv / (1.0f + __expf(-gv)) * uv);
      }
    }
#undef STAGEGLU
}

// ======== QKV GEMM, counted-vmcnt schedule + fused RoPE + direct V^T ========
__global__ __launch_bounds__(512, 4)
void gemm_qkv_big(const short* __restrict__ A, const short* __restrict__ Bt,
                  const float* __restrict__ tab, short* __restrict__ qbf,
                  short* __restrict__ kbf, short* __restrict__ vtbf, int K) {
  __shared__ short sA[2][128 * 64];
  __shared__ short sB[2][128 * 64];
  int bx = blockIdx.x, by = blockIdx.y;
  xcd_swizzle(gridDim.x, gridDim.y, bx, by);
  const int tid  = threadIdx.x;
  const int lane = tid & 63;
  const int wv   = tid >> 6;
  const int wm   = (wv >> 1) * 32;
  const int wn   = (wv & 1) * 64;
  const int row0 = by * 128;
  const int col0 = bx * 128;
  const int fr = lane & 15;
  const int g  = lane >> 4;
  const int NT = K >> 6;

  float4v acc[2][4] = {};

  int rS[2], cS[2];
  #pragma unroll
  for (int k = 0; k < 2; k++) {
    int s = tid + k * 512;
    rS[k] = s >> 3;
    cS[k] = (((s & 7) ^ (rS[k] & 7)) << 3);
  }

#define STAGEQKV(t, buf) do { \
    int k0_ = (t) << 6; \
    _Pragma("unroll") \
    for (int k_ = 0; k_ < 2; k_++) \
      GLOAD16(A  + (size_t)(row0 + rS[k_]) * K + k0_ + cS[k_], \
              &sA[buf][(tid + k_ * 512) * 8]); \
    _Pragma("unroll") \
    for (int k_ = 0; k_ < 2; k_++) \
      GLOAD16(Bt + (size_t)(col0 + rS[k_]) * K + k0_ + cS[k_], \
              &sB[buf][(tid + k_ * 512) * 8]); \
  } while (0)

  STAGEQKV(0, 0);

  for (int t = 0; t < NT; t++) {
    const int cur = t & 1;
    if (t + 1 < NT) {
      STAGEQKV(t + 1, cur ^ 1);
      asm volatile("s_waitcnt vmcnt(4)" ::: "memory");
    } else {
      asm volatile("s_waitcnt vmcnt(0)" ::: "memory");
    }
    __builtin_amdgcn_s_barrier();
    __builtin_amdgcn_sched_barrier(0);

    const short* pA = &sA[cur][wm * 64];
    const short* pB = &sB[cur][wn * 64];
    #pragma unroll
    for (int ks = 0; ks < 2; ks++) {
      const int fswk = ((((ks << 2) | g) ^ (fr & 7)) << 3);
      short8v afr[2], bfr[4];
      #pragma unroll
      for (int m2 = 0; m2 < 2; m2++)
        afr[m2] = *(const short8v*)(pA + (m2 * 16 + fr) * 64 + fswk);
      #pragma unroll
      for (int ni = 0; ni < 4; ni++)
        bfr[ni] = *(const short8v*)(pB + (ni * 16 + fr) * 64 + fswk);
      __builtin_amdgcn_s_setprio(1);
      #pragma unroll
      for (int m2 = 0; m2 < 2; m2++)
        #pragma unroll
        for (int ni = 0; ni < 4; ni++)
          acc[m2][ni] = __builtin_amdgcn_mfma_f32_16x16x32_bf16(
              afr[m2], bfr[ni], acc[m2][ni], 0, 0, 0);
      __builtin_amdgcn_s_setprio(0);
    }
    asm volatile("" ::: "memory");
    __builtin_amdgcn_s_barrier();
  }

  const int head = (col0 + wn) >> 6;
  if (head < HQ_ + HKV_) {
    const float sc = (head < HQ_) ? SCALE_ : 1.0f;
    short* dst = (head < HQ_) ? qbf : kbf;
    const int hh = (head < HQ_) ? head : head - HQ_;
    const int HN = (head < HQ_) ? HQ_ : HKV_;
    #pragma unroll
    for (int m2 = 0; m2 < 2; m2++)
      #pragma unroll
      for (int jj = 0; jj < 2; jj++)
        #pragma unroll
        for (int r = 0; r < 4; r++) {
          int m = row0 + wm + m2 * 16 + g * 4 + r;
          int b = m >> 10, s = m & (S_ - 1);
          int d1 = jj * 16 + fr;
          float x1 = acc[m2][jj][r], x2 = acc[m2][jj + 2][r];
          const float* tb = tab + (size_t)m * 64 + d1 * 2;
          float c = tb[0], sn = tb[1];
          size_t base = ((size_t)((b * HN + hh) * S_ + s)) * HD_;
          dst[base + d1]      = f2bf((x1 * c - x2 * sn) * sc);
          dst[base + d1 + 32] = f2bf((x2 * c + x1 * sn) * sc);
        }
  } else {
    // V head: write transposed layout vtbf[bkh][d][s] directly.
    const int vh = head - HQ_ - HKV_;
    #pragma unroll
    for (int m2 = 0; m2 < 2; m2++) {
      int m0 = row0 + wm + m2 * 16 + g * 4;
      int b = m0 >> 10, s0 = m0 & (S_ - 1);
      #pragma unroll
      for (int ni = 0; ni < 4; ni++) {
        int d = ni * 16 + fr;
        short4v w;
        #pragma unroll
        for (int r = 0; r < 4; r++) w[r] = f2bf(acc[m2][ni][r]);
        *(short4v*)(&vtbf[((size_t)((b * HKV_ + vh) * HD_ + d)) * S_ + s0]) = w;
      }
    }
  }
#undef STAGEQKV
}

// ---------------- RoPE cos/sin table: [T][32][2] f32 ----------------
__global__ __launch_bounds__(256)
void rope_table(const int* __restrict__ pos, float* __restrict__ tab) {
  int i = blockIdx.x * 256 + threadIdx.x;
  int t = i >> 5, ii = i & 31;
  float p = (float)pos[t];
  float freq = __expf(-(float)ii * (9.210340371976184f / 32.0f));
  float ang = p * freq;
  tab[2 * i]     = cosf(ang);
  tab[2 * i + 1] = sinf(ang);
}

#define KPAD 68

// ------- MFMA flash attention: wave-independent, K/V direct from L2 -------
// K/V panels per (b,kh) are 128 KB each -> L2-resident; no LDS staging, no
// barriers (m169).  Each wave owns 16 q-rows; sP is per-wave (wave-coherent).
// T13 defer-max + setprio kept.
__global__ __launch_bounds__(256)
void attn_mfma(const short* __restrict__ qbf, const short* __restrict__ kbf,
               const short* __restrict__ vtbf, short* __restrict__ obf) {
  __shared__ short sP[4][16 * KPAD];
  const int qblk = blockIdx.x;            // 16 blocks of 64 q-rows
  const int h  = blockIdx.y;
  const int b  = blockIdx.z;
  const int kh = h >> 2;
  const int tid  = threadIdx.x;
  const int lane = tid & 63;
  const int wv   = tid >> 6;              // 0..3
  const int q0 = qblk * 64 + wv * 16;     // this wave's 16 rows
  const int cc = lane & 15;
  const int g  = lane >> 4;

  short8v qf0, qf1;
  {
    const short* qrow = qbf + ((size_t)((b * HQ_ + h) * S_ + q0 + cc)) * HD_;
    qf0 = *(const short8v*)(qrow + g * 8);
    qf1 = *(const short8v*)(qrow + g * 8 + 32);
  }
  float4v accO[4] = {};
  float m_r[4], l_r[4];
  #pragma unroll
  for (int r = 0; r < 4; r++) { m_r[r] = -1e30f; l_r[r] = 0.f; }

  const short* kb = kbf  + ((size_t)(b * HKV_ + kh)) * S_ * HD_;
  const short* vb = vtbf + ((size_t)(b * HKV_ + kh)) * HD_ * S_;

  for (int jt = 0; jt <= qblk; jt++) {
    const int j0 = jt * 64;
    // QK^T: K fragments straight from global (L2 hits)
    float4v sc[4] = {};
    #pragma unroll
    for (int ct = 0; ct < 4; ct++) {
      const short* kr = kb + (size_t)(j0 + ct * 16 + cc) * HD_ + g * 8;
      short8v k0 = *(const short8v*)kr;
      short8v k1 = *(const short8v*)(kr + 32);
      __builtin_amdgcn_s_setprio(1);
      sc[ct] = __builtin_amdgcn_mfma_f32_16x16x32_bf16(qf0, k0, sc[ct], 0, 0, 0);
      sc[ct] = __builtin_amdgcn_mfma_f32_16x16x32_bf16(qf1, k1, sc[ct], 0, 0, 0);
      __builtin_amdgcn_s_setprio(0);
    }
    if (jt == qblk) {
      #pragma unroll
      for (int ct = 0; ct < 4; ct++)
        #pragma unroll
        for (int r = 0; r < 4; r++)
          if (j0 + ct * 16 + cc > q0 + g * 4 + r) sc[ct][r] = -1e30f;
    }
    float pmv[4], dmax = -1e30f;
    #pragma unroll
    for (int r = 0; r < 4; r++) {
      float pm = fmaxf(fmaxf(sc[0][r], sc[1][r]), fmaxf(sc[2][r], sc[3][r]));
      pm = fmaxf(pm, __shfl_xor(pm, 1, 64));
      pm = fmaxf(pm, __shfl_xor(pm, 2, 64));
      pm = fmaxf(pm, __shfl_xor(pm, 4, 64));
      pm = fmaxf(pm, __shfl_xor(pm, 8, 64));
      pmv[r] = pm;
      dmax = fmaxf(dmax, pm - m_r[r]);
    }
    if (!__all(dmax <= 8.0f)) {           // T13 defer-max
      float corr[4];
      #pragma unroll
      for (int r = 0; r < 4; r++) {
        float mn = fmaxf(m_r[r], pmv[r]);
        corr[r] = __expf(m_r[r] - mn);
        m_r[r] = mn;
        l_r[r] *= corr[r];
      }
      #pragma unroll
      for (int dt = 0; dt < 4; dt++)
        #pragma unroll
        for (int r = 0; r < 4; r++)
          accO[dt][r] *= corr[r];
    }
    #pragma unroll
    for (int r = 0; r < 4; r++) {
      float rs = 0.f;
      #pragma unroll
      for (int ct = 0; ct < 4; ct++) {
        float p = __expf(sc[ct][r] - m_r[r]);
        sc[ct][r] = p;
        rs += p;
      }
      rs += __shfl_xor(rs, 1, 64);
      rs += __shfl_xor(rs, 2, 64);
      rs += __shfl_xor(rs, 4, 64);
      rs += __shfl_xor(rs, 8, 64);
      l_r[r] += rs;
    }
    // P -> per-wave LDS (wave-coherent, no barrier needed)
    #pragma unroll
    for (int ct = 0; ct < 4; ct++)
      #pragma unroll
      for (int r = 0; r < 4; r++)
        sP[wv][(g * 4 + r) * KPAD + ct * 16 + cc] = f2bf(sc[ct][r]);
    short8v pf0 = *(const short8v*)(&sP[wv][cc * KPAD + g * 8]);
    short8v pf1 = *(const short8v*)(&sP[wv][cc * KPAD + g * 8 + 32]);
    // PV: V^T fragments straight from global (L2 hits)
    #pragma unroll
    for (int dt = 0; dt < 4; dt++) {
      const short* vr = vb + (size_t)(dt * 16 + cc) * S_ + j0 + g * 8;
      short8v v0 = *(const short8v*)vr;
      short8v v1 = *(const short8v*)(vr + 32);
      __builtin_amdgcn_s_setprio(1);
      accO[dt] = __builtin_amdgcn_mfma_f32_16x16x32_bf16(pf0, v0, accO[dt], 0, 0, 0);
      accO[dt] = __builtin_amdgcn_mfma_f32_16x16x32_bf16(pf1, v1, accO[dt], 0, 0, 0);
      __builtin_amdgcn_s_setprio(0);
    }
  }
  #pragma unroll
  for (int dt = 0; dt < 4; dt++)
    #pragma unroll
    for (int r = 0; r < 4; r++) {
      int q = q0 + g * 4 + r;
      obf[((size_t)(b * S_ + q)) * 2048 + h * 64 + dt * 16 + cc] = f2bf(accO[dt][r] / l_r[r]);
    }
}

// ---------------- launch ----------------
extern "C" void kernel_launch(void* const* d_in, const int* in_sizes, int n_in,
                              void* d_out, int out_size, void* d_ws, size_t ws_size,
                              hipStream_t stream) {
  const int*   ids   = (const int*)d_in[0];
  const int*   pos   = (const int*)d_in[1];
  const float* embed = (const float*)d_in[2];
  const float* w_qkv = (const float*)d_in[3];
  const float* w_o   = (const float*)d_in[4];
  const float* w_gu  = (const float*)d_in[5];
  const float* w_dn  = (const float*)d_in[6];
  const float* ln1   = (const float*)d_in[7];
  const float* ln2   = (const float*)d_in[8];
  const float* normw = (const float*)d_in[9];
  float* out = (float*)d_out;

  char* p = (char*)d_ws;
  short* wTq  = (short*)p; p += (size_t)2048 * 3072 * 2;
  short* wTo  = (short*)p; p += (size_t)2048 * 2048 * 2;
  short* wTgu = (short*)p; p += (size_t)2048 * 11264 * 2;
  short* wTdn = (short*)p; p += (size_t)5632 * 2048 * 2;
  float* h     = (float*)p; p += (size_t)T_ * D_ * 4;
  float* res   = (float*)p; p += (size_t)T_ * D_ * 4;
  short* hnbf  = (short*)p; p += (size_t)T_ * D_ * 2;
  short* obf   = (short*)p; p += (size_t)T_ * D_ * 2;
  short* mlpbf = (short*)p; p += (size_t)T_ * I_ * 2;
  float* tab   = (float*)p; p += (size_t)T_ * 64 * 4;
  short* qbf   = (short*)p; p += (size_t)B_ * HQ_ * S_ * HD_ * 2;
  short* kbf   = (short*)p; p += (size_t)B_ * HKV_ * S_ * HD_ * 2;
  short* vtbf  = (short*)p; p += (size_t)B_ * HKV_ * HD_ * S_ * 2;

  embed_gather<<<T_ * D_ / 4 / 256, 256, 0, stream>>>(ids, embed, h);
  rope_table<<<T_ * 32 / 256, 256, 0, stream>>>(pos, tab);

  for (int l = 0; l < L_; l++) {
    transpose_layer<<<5504, 256, 0, stream>>>(
        w_qkv + (size_t)l * 2048 * 3072, w_o + (size_t)l * 2048 * 2048,
        w_gu + (size_t)l * 2048 * 11264, w_dn + (size_t)l * 5632 * 2048,
        wTq, wTo, wTgu, wTdn);

    rmsnorm_kernel<<<T_, 256, 0, stream>>>(h, res, ln1 + l * D_, hnbf,
                                           l == 0 ? 1 : 0, 1);

    gemm_qkv_big<<<dim3(3072 / 128, T_ / 128), 512, 0, stream>>>(
        hnbf, wTq, tab, qbf, kbf, vtbf, 2048);

    attn_mfma<<<dim3(16, 32, 2), 256, 0, stream>>>(qbf, kbf, vtbf, obf);

    gemm_big128<<<dim3(2048 / 128, T_ / 128), 512, 0, stream>>>(
        obf, wTo, res, T_, 2048, 2048, 1);          // res += o_proj

    rmsnorm_kernel<<<T_, 256, 0, stream>>>(nullptr, res, ln2 + l * D_, hnbf, 0, 1);

    gemm_glu_big<<<dim3(I_ / 128, T_ / 128), 512, 0, stream>>>(
        hnbf, wTgu, mlpbf, 2048);

    gemm_big128<<<dim3(2048 / 128, T_ / 128), 512, 0, stream>>>(
        mlpbf, wTdn, res, T_, 2048, 5632, 1);       // res += down_proj
  }
  rmsnorm_kernel<<<T_, 256, 0, stream>>>(nullptr, res, normw, out, 0, 0);
}

// Round 15
// 1675.266 us; speedup vs baseline: 1.1929x; 1.1929x over previous
//
#include <hip/hip_runtime.h>
#include <hip/hip_bf16.h>

#define B_ 2
#define S_ 1024
#define T_ (B_*S_)
#define D_ 2048
#define L_ 4
#define HQ_ 32
#define HKV_ 8
#define HD_ 64
#define I_ 5632
#define EPS_ 1e-5f
#define SCALE_ 0.125f

typedef __attribute__((ext_vector_type(4))) float  float4v;
typedef __attribute__((ext_vector_type(8))) short  short8v;
typedef __attribute__((ext_vector_type(4))) short  short4v;

#define GLOAD16(g, l) \
  __builtin_amdgcn_global_load_lds((const __attribute__((address_space(1))) void*)(g), \
                                   (__attribute__((address_space(3))) void*)(l), 16, 0, 0)

__device__ __forceinline__ short f2bf(float f) {
  union { float f; unsigned u; } c; c.f = f;
  unsigned u = c.u + 0x7fffu + ((c.u >> 16) & 1u);
  return (short)(u >> 16);
}

// bijective XCD-aware block swizzle (m204), column-major decode
__device__ __forceinline__ void xcd_swizzle(int gx, int gy, int& bx, int& by) {
  int nwg = gx * gy;
  int orig = by * gx + bx;
  int q = nwg >> 3, r = nwg & 7;
  int xcd = orig & 7, loc = orig >> 3;
  int swz = (xcd < r ? xcd * (q + 1) : r * (q + 1) + (xcd - r) * q) + loc;
  bx = swz / gy;
  by = swz - bx * gy;
}

// ------- ONE layer's weight transposes f32 [K][N] -> bf16 [N][K], one launch -------
// JIT per layer: outputs (90 MB) are consumed by this layer's GEMMs while
// still LLC-resident.  Flat blockIdx.x decodes {qkv, o, gu, dn}.
__global__ __launch_bounds__(256)
void transpose_layer(const float* __restrict__ wq, const float* __restrict__ wo,
                     const float* __restrict__ wg, const float* __restrict__ wd,
                     short* __restrict__ tq, short* __restrict__ to_,
                     short* __restrict__ tg, short* __restrict__ td) {
  int id = blockIdx.x;
  const float* in; short* out; int K, N, bxt, byt;
  if (id < 1536)      { in = wq; out = tq;
                        K = 2048; N = 3072;  bxt = id % 48;  byt = id / 48; }
  else if (id < 2560) { id -= 1536; in = wo; out = to_;
                        K = 2048; N = 2048;  bxt = id % 32;  byt = id / 32; }
  else if (id < 8192) { id -= 2560; in = wg; out = tg;
                        K = 2048; N = 11264; bxt = id % 176; byt = id / 176; }
  else                { id -= 8192; in = wd; out = td;
                        K = 5632; N = 2048;  bxt = id % 32;  byt = id / 32; }
  __shared__ float t[64][65];
  const int bx = bxt * 64;   // N
  const int by = byt * 64;   // K
  const int tid = threadIdx.x;
  const int lr = tid >> 4;
  const int lc = (tid & 15) * 4;
  #pragma unroll
  for (int j = 0; j < 64; j += 16) {
    float4v v = *(const float4v*)(in + (size_t)(by + lr + j) * N + bx + lc);
    t[lr + j][lc] = v[0]; t[lr + j][lc + 1] = v[1];
    t[lr + j][lc + 2] = v[2]; t[lr + j][lc + 3] = v[3];
  }
  __syncthreads();
  const int nr = tid >> 3;
  const int kc = (tid & 7) * 8;
  #pragma unroll
  for (int j = 0; j < 64; j += 32) {
    short8v y;
    #pragma unroll
    for (int e = 0; e < 8; e++) y[e] = f2bf(t[kc + e][nr + j]);
    *(short8v*)(out + (size_t)(bx + nr + j) * K + by + kc) = y;
  }
}

// ---------------- embedding gather ----------------
__global__ __launch_bounds__(256)
void embed_gather(const int* __restrict__ ids, const float* __restrict__ embed,
                  float* __restrict__ h) {
  size_t i = (size_t)blockIdx.x * 256 + threadIdx.x;
  int t  = (int)(i >> 9);
  int d4 = (int)(i & 511);
  ((float4v*)h)[i] = ((const float4v*)(embed + (size_t)ids[t] * D_))[d4];
}

// ------- RMSNorm: first -> res = x, else pure read of res; out f32/bf16 -------
__global__ __launch_bounds__(256)
void rmsnorm_kernel(const float* __restrict__ x, float* __restrict__ res,
                    const float* __restrict__ w, void* __restrict__ outp,
                    int first, int bf16out) {
  const int row = blockIdx.x;
  const int tid = threadIdx.x;
  const size_t base = (size_t)row * D_;
  float4v v0, v1;
  if (first) {
    v0 = ((const float4v*)(x + base))[tid * 2];
    v1 = ((const float4v*)(x + base))[tid * 2 + 1];
    ((float4v*)(res + base))[tid * 2]     = v0;
    ((float4v*)(res + base))[tid * 2 + 1] = v1;
  } else {
    v0 = ((const float4v*)(res + base))[tid * 2];
    v1 = ((const float4v*)(res + base))[tid * 2 + 1];
  }
  float ss = v0[0]*v0[0] + v0[1]*v0[1] + v0[2]*v0[2] + v0[3]*v0[3]
           + v1[0]*v1[0] + v1[1]*v1[1] + v1[2]*v1[2] + v1[3]*v1[3];
  #pragma unroll
  for (int off = 32; off > 0; off >>= 1) ss += __shfl_xor(ss, off, 64);
  __shared__ float red[4];
  if ((tid & 63) == 0) red[tid >> 6] = ss;
  __syncthreads();
  float tot = red[0] + red[1] + red[2] + red[3];
  float rs = rsqrtf(tot * (1.0f / D_) + EPS_);
  float4v w0 = ((const float4v*)w)[tid * 2];
  float4v w1 = ((const float4v*)w)[tid * 2 + 1];
  float4v o0 = v0 * rs * w0;
  float4v o1 = v1 * rs * w1;
  if (bf16out) {
    short8v y;
    #pragma unroll
    for (int k = 0; k < 4; k++) { y[k] = f2bf(o0[k]); y[k + 4] = f2bf(o1[k]); }
    ((short8v*)((char*)outp + base * 2))[tid] = y;
  } else {
    float* op = (float*)outp + base;
    ((float4v*)op)[tid * 2]     = o0;
    ((float4v*)op)[tid * 2 + 1] = o1;
  }
}

// ======== 128x128 8-wave GEMM, counted vmcnt(4) + T2 swizzle + setprio ========
__global__ __launch_bounds__(512, 4)
void gemm_big128(const short* __restrict__ A, const short* __restrict__ Bt,
                 float* __restrict__ C, int M, int N, int K, int addto) {
  __shared__ short sA[2][128 * 64];
  __shared__ short sB[2][128 * 64];
  int bx = blockIdx.x, by = blockIdx.y;
  xcd_swizzle(gridDim.x, gridDim.y, bx, by);
  const int tid  = threadIdx.x;
  const int lane = tid & 63;
  const int wv   = tid >> 6;
  const int wr   = wv >> 2;
  const int wc   = wv & 3;
  const int row0 = by * 128;
  const int col0 = bx * 128;
  const int fr = lane & 15;
  const int g  = lane >> 4;
  const int NT = K >> 6;

  float4v acc[4][2] = {};

  int rS[2], cS[2];
  #pragma unroll
  for (int k = 0; k < 2; k++) {
    int s = tid + k * 512;
    rS[k] = s >> 3;
    cS[k] = (((s & 7) ^ (rS[k] & 7)) << 3);
  }

#define STAGE128(t, buf) do { \
    int k0_ = (t) << 6; \
    _Pragma("unroll") \
    for (int k_ = 0; k_ < 2; k_++) \
      GLOAD16(A  + (size_t)(row0 + rS[k_]) * K + k0_ + cS[k_], \
              &sA[buf][(tid + k_ * 512) * 8]); \
    _Pragma("unroll") \
    for (int k_ = 0; k_ < 2; k_++) \
      GLOAD16(Bt + (size_t)(col0 + rS[k_]) * K + k0_ + cS[k_], \
              &sB[buf][(tid + k_ * 512) * 8]); \
  } while (0)

  STAGE128(0, 0);

  for (int t = 0; t < NT; t++) {
    const int cur = t & 1;
    if (t + 1 < NT) {
      STAGE128(t + 1, cur ^ 1);
      asm volatile("s_waitcnt vmcnt(4)" ::: "memory");
    } else {
      asm volatile("s_waitcnt vmcnt(0)" ::: "memory");
    }
    __builtin_amdgcn_s_barrier();
    __builtin_amdgcn_sched_barrier(0);

    const short* pA = &sA[cur][(wr * 64) * 64];
    const short* pB = &sB[cur][(wc * 32) * 64];
    #pragma unroll
    for (int ks = 0; ks < 2; ks++) {
      const int fswk = ((((ks << 2) | g) ^ (fr & 7)) << 3);
      short8v bfr[2], afr[4];
      #pragma unroll
      for (int ni = 0; ni < 2; ni++)
        bfr[ni] = *(const short8v*)(pB + (ni * 16 + fr) * 64 + fswk);
      #pragma unroll
      for (int m4 = 0; m4 < 4; m4++)
        afr[m4] = *(const short8v*)(pA + (m4 * 16 + fr) * 64 + fswk);
      __builtin_amdgcn_s_setprio(1);
      #pragma unroll
      for (int m4 = 0; m4 < 4; m4++)
        #pragma unroll
        for (int ni = 0; ni < 2; ni++)
          acc[m4][ni] = __builtin_amdgcn_mfma_f32_16x16x32_bf16(
              afr[m4], bfr[ni], acc[m4][ni], 0, 0, 0);
      __builtin_amdgcn_s_setprio(0);
    }
    asm volatile("" ::: "memory");
    __builtin_amdgcn_s_barrier();
  }

  #pragma unroll
  for (int m4 = 0; m4 < 4; m4++)
    #pragma unroll
    for (int ni = 0; ni < 2; ni++) {
      size_t base = (size_t)(row0 + wr * 64 + m4 * 16 + g * 4) * N
                    + col0 + wc * 32 + ni * 16 + fr;
      if (addto) {
        #pragma unroll
        for (int r = 0; r < 4; r++)
          C[base + (size_t)r * N] += acc[m4][ni][r];
      } else {
        #pragma unroll
        for (int r = 0; r < 4; r++)
          C[base + (size_t)r * N] = acc[m4][ni][r];
      }
    }
#undef STAGE128
}

// ======== gate_up GEMM + fused SwiGLU on the same schedule, vmcnt(6) ========
__global__ __launch_bounds__(512, 2)
void gemm_glu_big(const short* __restrict__ A, const short* __restrict__ Bt,
                  short* __restrict__ mlp, int K) {
  __shared__ short sA[2][128 * 64];
  __shared__ short sG[2][128 * 64];
  __shared__ short sU[2][128 * 64];
  int bx = blockIdx.x, by = blockIdx.y;
  xcd_swizzle(gridDim.x, gridDim.y, bx, by);
  const int tid  = threadIdx.x;
  const int lane = tid & 63;
  const int wv   = tid >> 6;
  const int wr   = wv >> 2;
  const int wc   = wv & 3;
  const int row0 = by * 128;
  const int col0 = bx * 128;
  const int fr = lane & 15;
  const int g  = lane >> 4;
  const int NT = K >> 6;

  float4v accg[4][2] = {};
  float4v accu[4][2] = {};

  int rS[2], cS[2];
  #pragma unroll
  for (int k = 0; k < 2; k++) {
    int s = tid + k * 512;
    rS[k] = s >> 3;
    cS[k] = (((s & 7) ^ (rS[k] & 7)) << 3);
  }

#define STAGEGLU(t, buf) do { \
    int k0_ = (t) << 6; \
    _Pragma("unroll") \
    for (int k_ = 0; k_ < 2; k_++) \
      GLOAD16(A  + (size_t)(row0 + rS[k_]) * K + k0_ + cS[k_], \
              &sA[buf][(tid + k_ * 512) * 8]); \
    _Pragma("unroll") \
    for (int k_ = 0; k_ < 2; k_++) \
      GLOAD16(Bt + (size_t)(col0 + rS[k_]) * K + k0_ + cS[k_], \
              &sG[buf][(tid + k_ * 512) * 8]); \
    _Pragma("unroll") \
    for (int k_ = 0; k_ < 2; k_++) \
      GLOAD16(Bt + (size_t)(col0 + I_ + rS[k_]) * K + k0_ + cS[k_], \
              &sU[buf][(tid + k_ * 512) * 8]); \
  } while (0)

  STAGEGLU(0, 0);

  for (int t = 0; t < NT; t++) {
    const int cur = t & 1;
    if (t + 1 < NT) {
      STAGEGLU(t + 1, cur ^ 1);
      asm volatile("s_waitcnt vmcnt(6)" ::: "memory");
    } else {
      asm volatile("s_waitcnt vmcnt(0)" ::: "memory");
    }
    __builtin_amdgcn_s_barrier();
    __builtin_amdgcn_sched_barrier(0);

    const short* pA = &sA[cur][(wr * 64) * 64];
    const short* pG = &sG[cur][(wc * 32) * 64];
    const short* pU = &sU[cur][(wc * 32) * 64];
    #pragma unroll
    for (int ks = 0; ks < 2; ks++) {
      const int fswk = ((((ks << 2) | g) ^ (fr & 7)) << 3);
      short8v bg[2], bu[2], afr[4];
      #pragma unroll
      for (int ni = 0; ni < 2; ni++) {
        bg[ni] = *(const short8v*)(pG + (ni * 16 + fr) * 64 + fswk);
        bu[ni] = *(const short8v*)(pU + (ni * 16 + fr) * 64 + fswk);
      }
      #pragma unroll
      for (int m4 = 0; m4 < 4; m4++)
        afr[m4] = *(const short8v*)(pA + (m4 * 16 + fr) * 64 + fswk);
      __builtin_amdgcn_s_setprio(1);
      #pragma unroll
      for (int m4 = 0; m4 < 4; m4++)
        #pragma unroll
        for (int ni = 0; ni < 2; ni++) {
          accg[m4][ni] = __builtin_amdgcn_mfma_f32_16x16x32_bf16(
              afr[m4], bg[ni], accg[m4][ni], 0, 0, 0);
          accu[m4][ni] = __builtin_amdgcn_mfma_f32_16x16x32_bf16(
              afr[m4], bu[ni], accu[m4][ni], 0, 0, 0);
        }
      __builtin_amdgcn_s_setprio(0);
    }
    asm volatile("" ::: "memory");
    __builtin_amdgcn_s_barrier();
  }

  #pragma unroll
  for (int m4 = 0; m4 < 4; m4++)
    #pragma unroll
    for (int ni = 0; ni < 2; ni++) {
      size_t base = (size_t)(row0 + wr * 64 + m4 * 16 + g * 4) * I_
                    + col0 + wc * 32 + ni * 16 + fr;
      #pragma unroll
      for (int r = 0; r < 4; r++) {
        float gv = accg[m4][ni][r], uv = accu[m4][ni][r];
        mlp[base + (size_t)r * I_] = f2bf(gv / (1.0f + __expf(-gv)) * uv);
      }
    }
#undef STAGEGLU
}

// ======== QKV GEMM, counted-vmcnt schedule + fused RoPE + direct V^T ========
__global__ __launch_bounds__(512, 4)
void gemm_qkv_big(const short* __restrict__ A, const short* __restrict__ Bt,
                  const float* __restrict__ tab, short* __restrict__ qbf,
                  short* __restrict__ kbf, short* __restrict__ vtbf, int K) {
  __shared__ short sA[2][128 * 64];
  __shared__ short sB[2][128 * 64];
  int bx = blockIdx.x, by = blockIdx.y;
  xcd_swizzle(gridDim.x, gridDim.y, bx, by);
  const int tid  = threadIdx.x;
  const int lane = tid & 63;
  const int wv   = tid >> 6;
  const int wm   = (wv >> 1) * 32;
  const int wn   = (wv & 1) * 64;
  const int row0 = by * 128;
  const int col0 = bx * 128;
  const int fr = lane & 15;
  const int g  = lane >> 4;
  const int NT = K >> 6;

  float4v acc[2][4] = {};

  int rS[2], cS[2];
  #pragma unroll
  for (int k = 0; k < 2; k++) {
    int s = tid + k * 512;
    rS[k] = s >> 3;
    cS[k] = (((s & 7) ^ (rS[k] & 7)) << 3);
  }

#define STAGEQKV(t, buf) do { \
    int k0_ = (t) << 6; \
    _Pragma("unroll") \
    for (int k_ = 0; k_ < 2; k_++) \
      GLOAD16(A  + (size_t)(row0 + rS[k_]) * K + k0_ + cS[k_], \
              &sA[buf][(tid + k_ * 512) * 8]); \
    _Pragma("unroll") \
    for (int k_ = 0; k_ < 2; k_++) \
      GLOAD16(Bt + (size_t)(col0 + rS[k_]) * K + k0_ + cS[k_], \
              &sB[buf][(tid + k_ * 512) * 8]); \
  } while (0)

  STAGEQKV(0, 0);

  for (int t = 0; t < NT; t++) {
    const int cur = t & 1;
    if (t + 1 < NT) {
      STAGEQKV(t + 1, cur ^ 1);
      asm volatile("s_waitcnt vmcnt(4)" ::: "memory");
    } else {
      asm volatile("s_waitcnt vmcnt(0)" ::: "memory");
    }
    __builtin_amdgcn_s_barrier();
    __builtin_amdgcn_sched_barrier(0);

    const short* pA = &sA[cur][wm * 64];
    const short* pB = &sB[cur][wn * 64];
    #pragma unroll
    for (int ks = 0; ks < 2; ks++) {
      const int fswk = ((((ks << 2) | g) ^ (fr & 7)) << 3);
      short8v afr[2], bfr[4];
      #pragma unroll
      for (int m2 = 0; m2 < 2; m2++)
        afr[m2] = *(const short8v*)(pA + (m2 * 16 + fr) * 64 + fswk);
      #pragma unroll
      for (int ni = 0; ni < 4; ni++)
        bfr[ni] = *(const short8v*)(pB + (ni * 16 + fr) * 64 + fswk);
      __builtin_amdgcn_s_setprio(1);
      #pragma unroll
      for (int m2 = 0; m2 < 2; m2++)
        #pragma unroll
        for (int ni = 0; ni < 4; ni++)
          acc[m2][ni] = __builtin_amdgcn_mfma_f32_16x16x32_bf16(
              afr[m2], bfr[ni], acc[m2][ni], 0, 0, 0);
      __builtin_amdgcn_s_setprio(0);
    }
    asm volatile("" ::: "memory");
    __builtin_amdgcn_s_barrier();
  }

  const int head = (col0 + wn) >> 6;
  if (head < HQ_ + HKV_) {
    const float sc = (head < HQ_) ? SCALE_ : 1.0f;
    short* dst = (head < HQ_) ? qbf : kbf;
    const int hh = (head < HQ_) ? head : head - HQ_;
    const int HN = (head < HQ_) ? HQ_ : HKV_;
    #pragma unroll
    for (int m2 = 0; m2 < 2; m2++)
      #pragma unroll
      for (int jj = 0; jj < 2; jj++)
        #pragma unroll
        for (int r = 0; r < 4; r++) {
          int m = row0 + wm + m2 * 16 + g * 4 + r;
          int b = m >> 10, s = m & (S_ - 1);
          int d1 = jj * 16 + fr;
          float x1 = acc[m2][jj][r], x2 = acc[m2][jj + 2][r];
          const float* tb = tab + (size_t)m * 64 + d1 * 2;
          float c = tb[0], sn = tb[1];
          size_t base = ((size_t)((b * HN + hh) * S_ + s)) * HD_;
          dst[base + d1]      = f2bf((x1 * c - x2 * sn) * sc);
          dst[base + d1 + 32] = f2bf((x2 * c + x1 * sn) * sc);
        }
  } else {
    // V head: write transposed layout vtbf[bkh][d][s] directly.
    const int vh = head - HQ_ - HKV_;
    #pragma unroll
    for (int m2 = 0; m2 < 2; m2++) {
      int m0 = row0 + wm + m2 * 16 + g * 4;
      int b = m0 >> 10, s0 = m0 & (S_ - 1);
      #pragma unroll
      for (int ni = 0; ni < 4; ni++) {
        int d = ni * 16 + fr;
        short4v w;
        #pragma unroll
        for (int r = 0; r < 4; r++) w[r] = f2bf(acc[m2][ni][r]);
        *(short4v*)(&vtbf[((size_t)((b * HKV_ + vh) * HD_ + d)) * S_ + s0]) = w;
      }
    }
  }
#undef STAGEQKV
}

// ---------------- RoPE cos/sin table: [T][32][2] f32 ----------------
__global__ __launch_bounds__(256)
void rope_table(const int* __restrict__ pos, float* __restrict__ tab) {
  int i = blockIdx.x * 256 + threadIdx.x;
  int t = i >> 5, ii = i & 31;
  float p = (float)pos[t];
  float freq = __expf(-(float)ii * (9.210340371976184f / 32.0f));
  float ang = p * freq;
  tab[2 * i]     = cosf(ang);
  tab[2 * i + 1] = sinf(ang);
}

#define KPAD 68

// ------- MFMA flash attention, QBLK=128 (8 waves), T14 split + T13 defer-max -------
__global__ __launch_bounds__(512)
void attn_mfma(const short* __restrict__ qbf, const short* __restrict__ kbf,
               const short* __restrict__ vtbf, short* __restrict__ obf) {
  __shared__ short sK[64 * KPAD];
  __shared__ short sVt[64 * KPAD];
  __shared__ short sP[8][16 * KPAD];
  const int qb = blockIdx.x;
  const int h  = blockIdx.y;
  const int b  = blockIdx.z;
  const int kh = h >> 2;
  const int tid  = threadIdx.x;
  const int lane = tid & 63;
  const int wv   = tid >> 6;
  const int q0 = qb * 128;
  const int cc = lane & 15;
  const int g  = lane >> 4;

  short8v qf0, qf1;
  {
    const short* qrow = qbf + ((size_t)((b * HQ_ + h) * S_ + q0 + wv * 16 + cc)) * HD_;
    qf0 = *(const short8v*)(qrow + g * 8);
    qf1 = *(const short8v*)(qrow + g * 8 + 32);
  }
  float4v accO[4] = {};
  float m_r[4], l_r[4];
  #pragma unroll
  for (int r = 0; r < 4; r++) { m_r[r] = -1e30f; l_r[r] = 0.f; }

  const short* kb = kbf  + ((size_t)(b * HKV_ + kh)) * S_ * HD_;
  const short* vb = vtbf + ((size_t)(b * HKV_ + kh)) * HD_ * S_;

  const int rr = tid >> 3;
  const int ch = (tid & 7) * 8;

  short8v kr = *(const short8v*)(kb + (size_t)rr * HD_ + ch);
  short8v vr = *(const short8v*)(vb + (size_t)rr * S_ + ch);

  const int nb = 2 * qb + 1;
  for (int jt = 0; jt <= nb; jt++) {
    const int j0 = jt * 64;
    __syncthreads();
    *(short8v*)(&sK[rr * KPAD + ch])  = kr;
    *(short8v*)(&sVt[rr * KPAD + ch]) = vr;
    __syncthreads();

    if (jt < nb) {
      const int j0n = j0 + 64;
      kr = *(const short8v*)(kb + (size_t)(j0n + rr) * HD_ + ch);
      vr = *(const short8v*)(vb + (size_t)rr * S_ + j0n + ch);
    }

    float4v sc[4] = {};
    #pragma unroll
    for (int ct = 0; ct < 4; ct++) {
      short8v k0 = *(const short8v*)(&sK[(ct * 16 + cc) * KPAD + g * 8]);
      short8v k1 = *(const short8v*)(&sK[(ct * 16 + cc) * KPAD + g * 8 + 32]);
      __builtin_amdgcn_s_setprio(1);
      sc[ct] = __builtin_amdgcn_mfma_f32_16x16x32_bf16(qf0, k0, sc[ct], 0, 0, 0);
      sc[ct] = __builtin_amdgcn_mfma_f32_16x16x32_bf16(qf1, k1, sc[ct], 0, 0, 0);
      __builtin_amdgcn_s_setprio(0);
    }
    if (jt >= 2 * qb) {
      #pragma unroll
      for (int ct = 0; ct < 4; ct++)
        #pragma unroll
        for (int r = 0; r < 4; r++)
          if (j0 + ct * 16 + cc > q0 + wv * 16 + g * 4 + r) sc[ct][r] = -1e30f;
    }
    float pmv[4], dmax = -1e30f;
    #pragma unroll
    for (int r = 0; r < 4; r++) {
      float pm = fmaxf(fmaxf(sc[0][r], sc[1][r]), fmaxf(sc[2][r], sc[3][r]));
      pm = fmaxf(pm, __shfl_xor(pm, 1, 64));
      pm = fmaxf(pm, __shfl_xor(pm, 2, 64));
      pm = fmaxf(pm, __shfl_xor(pm, 4, 64));
      pm = fmaxf(pm, __shfl_xor(pm, 8, 64));
      pmv[r] = pm;
      dmax = fmaxf(dmax, pm - m_r[r]);
    }
    if (!__all(dmax <= 8.0f)) {
      float corr[4];
      #pragma unroll
      for (int r = 0; r < 4; r++) {
        float mn = fmaxf(m_r[r], pmv[r]);
        corr[r] = __expf(m_r[r] - mn);
        m_r[r] = mn;
        l_r[r] *= corr[r];
      }
      #pragma unroll
      for (int dt = 0; dt < 4; dt++)
        #pragma unroll
        for (int r = 0; r < 4; r++)
          accO[dt][r] *= corr[r];
    }
    #pragma unroll
    for (int r = 0; r < 4; r++) {
      float rs = 0.f;
      #pragma unroll
      for (int ct = 0; ct < 4; ct++) {
        float p = __expf(sc[ct][r] - m_r[r]);
        sc[ct][r] = p;
        rs += p;
      }
      rs += __shfl_xor(rs, 1, 64);
      rs += __shfl_xor(rs, 2, 64);
      rs += __shfl_xor(rs, 4, 64);
      rs += __shfl_xor(rs, 8, 64);
      l_r[r] += rs;
    }
    #pragma unroll
    for (int ct = 0; ct < 4; ct++)
      #pragma unroll
      for (int r = 0; r < 4; r++)
        sP[wv][(g * 4 + r) * KPAD + ct * 16 + cc] = f2bf(sc[ct][r]);
    short8v pf0 = *(const short8v*)(&sP[wv][cc * KPAD + g * 8]);
    short8v pf1 = *(const short8v*)(&sP[wv][cc * KPAD + g * 8 + 32]);
    #pragma unroll
    for (int dt = 0; dt < 4; dt++) {
      short8v v0 = *(const short8v*)(&sVt[(dt * 16 + cc) * KPAD + g * 8]);
      short8v v1 = *(const short8v*)(&sVt[(dt * 16 + cc) * KPAD + g * 8 + 32]);
      __builtin_amdgcn_s_setprio(1);
      accO[dt] = __builtin_amdgcn_mfma_f32_16x16x32_bf16(pf0, v0, accO[dt], 0, 0, 0);
      accO[dt] = __builtin_amdgcn_mfma_f32_16x16x32_bf16(pf1, v1, accO[dt], 0, 0, 0);
      __builtin_amdgcn_s_setprio(0);
    }
  }
  #pragma unroll
  for (int dt = 0; dt < 4; dt++)
    #pragma unroll
    for (int r = 0; r < 4; r++) {
      int q = q0 + wv * 16 + g * 4 + r;
      obf[((size_t)(b * S_ + q)) * 2048 + h * 64 + dt * 16 + cc] = f2bf(accO[dt][r] / l_r[r]);
    }
}

// ---------------- launch ----------------
extern "C" void kernel_launch(void* const* d_in, const int* in_sizes, int n_in,
                              void* d_out, int out_size, void* d_ws, size_t ws_size,
                              hipStream_t stream) {
  const int*   ids   = (const int*)d_in[0];
  const int*   pos   = (const int*)d_in[1];
  const float* embed = (const float*)d_in[2];
  const float* w_qkv = (const float*)d_in[3];
  const float* w_o   = (const float*)d_in[4];
  const float* w_gu  = (const float*)d_in[5];
  const float* w_dn  = (const float*)d_in[6];
  const float* ln1   = (const float*)d_in[7];
  const float* ln2   = (const float*)d_in[8];
  const float* normw = (const float*)d_in[9];
  float* out = (float*)d_out;

  char* p = (char*)d_ws;
  // per-layer rotating weight-T buffers (JIT, LLC-resident): 90 MB total
  short* wTq  = (short*)p; p += (size_t)2048 * 3072 * 2;
  short* wTo  = (short*)p; p += (size_t)2048 * 2048 * 2;
  short* wTgu = (short*)p; p += (size_t)2048 * 11264 * 2;
  short* wTdn = (short*)p; p += (size_t)5632 * 2048 * 2;
  float* h     = (float*)p; p += (size_t)T_ * D_ * 4;
  float* res   = (float*)p; p += (size_t)T_ * D_ * 4;
  short* hnbf  = (short*)p; p += (size_t)T_ * D_ * 2;
  short* obf   = (short*)p; p += (size_t)T_ * D_ * 2;
  short* mlpbf = (short*)p; p += (size_t)T_ * I_ * 2;
  float* tab   = (float*)p; p += (size_t)T_ * 64 * 4;
  short* qbf   = (short*)p; p += (size_t)B_ * HQ_ * S_ * HD_ * 2;
  short* kbf   = (short*)p; p += (size_t)B_ * HKV_ * S_ * HD_ * 2;
  short* vtbf  = (short*)p; p += (size_t)B_ * HKV_ * HD_ * S_ * 2;

  embed_gather<<<T_ * D_ / 4 / 256, 256, 0, stream>>>(ids, embed, h);
  rope_table<<<T_ * 32 / 256, 256, 0, stream>>>(pos, tab);

  for (int l = 0; l < L_; l++) {
    // JIT: this layer's 4 weight transposes in one launch; outputs stay in LLC
    transpose_layer<<<11008, 256, 0, stream>>>(
        w_qkv + (size_t)l * 2048 * 3072, w_o + (size_t)l * 2048 * 2048,
        w_gu + (size_t)l * 2048 * 11264, w_dn + (size_t)l * 5632 * 2048,
        wTq, wTo, wTgu, wTdn);

    rmsnorm_kernel<<<T_, 256, 0, stream>>>(h, res, ln1 + l * D_, hnbf,
                                           l == 0 ? 1 : 0, 1);

    gemm_qkv_big<<<dim3(3072 / 128, T_ / 128), 512, 0, stream>>>(
        hnbf, wTq, tab, qbf, kbf, vtbf, 2048);

    attn_mfma<<<dim3(8, 32, 2), 512, 0, stream>>>(qbf, kbf, vtbf, obf);

    gemm_big128<<<dim3(2048 / 128, T_ / 128), 512, 0, stream>>>(
        obf, wTo, res, T_, 2048, 2048, 1);          // res += o_proj

    rmsnorm_kernel<<<T_, 256, 0, stream>>>(nullptr, res, ln2 + l * D_, hnbf, 0, 1);

    gemm_glu_big<<<dim3(I_ / 128, T_ / 128), 512, 0, stream>>>(
        hnbf, wTgu, mlpbf, 2048);

    gemm_big128<<<dim3(2048 / 128, T_ / 128), 512, 0, stream>>>(
        mlpbf, wTdn, res, T_, 2048, 5632, 1);       // res += down_proj
  }
  rmsnorm_kernel<<<T_, 256, 0, stream>>>(nullptr, res, normw, out, 0, 0);
}